// Round 1
// baseline (1358.008 us; speedup 1.0000x reference)
//
#include <hip/hip_runtime.h>
#include <math.h>

typedef __bf16 bf16x8 __attribute__((ext_vector_type(8)));
typedef float f32x4 __attribute__((ext_vector_type(4)));
typedef short s16x4 __attribute__((ext_vector_type(4)));
typedef short s16x8 __attribute__((ext_vector_type(8)));

static __device__ __forceinline__ short f2bs(float f) {
  return __builtin_bit_cast(short, (__bf16)f);
}

#define GLL16(gp, lp) __builtin_amdgcn_global_load_lds( \
    (const __attribute__((address_space(1))) void*)(gp), \
    (__attribute__((address_space(3))) void*)(lp), 16, 0, 0)

// ---------------------------------------------------------------- conversions
__global__ __launch_bounds__(256) void cvt_f32_bf16(const float* __restrict__ s,
                                                    short* __restrict__ d, int n) {
  int stride = gridDim.x * blockDim.x * 4;
  for (int j = (blockIdx.x * blockDim.x + threadIdx.x) * 4; j < n; j += stride) {
    float4 v = *(const float4*)(s + j);
    s16x4 o;
    o[0] = f2bs(v.x); o[1] = f2bs(v.y); o[2] = f2bs(v.z); o[3] = f2bs(v.w);
    *(s16x4*)(d + j) = o;
  }
}

// pad K 588 -> 608 with zeros, row-major
__global__ __launch_bounds__(256) void cvt_pad(const float* __restrict__ s,
                                               short* __restrict__ d) {
  int r = blockIdx.x;
  for (int c = threadIdx.x; c < 608; c += blockDim.x)
    d[(size_t)r * 608 + c] = (c < 588) ? f2bs(s[(size_t)r * 588 + c]) : (short)0;
}

// ---------------------------------------------------------------- GEMM
// C[M=4096,N] = A[M,K](bf16) @ B[N,K](bf16)^T + bias, epilogue variants.
// EPI: 0 = bf16 out, 1 = bf16 + exact GELU, 2 = f32 + residual, 3 = f32
template <int N, int K, int EPI>
__global__ __launch_bounds__(256) void gemm_bt(const short* __restrict__ A,
                                               const short* __restrict__ B,
                                               const float* __restrict__ bias,
                                               const float* resid, void* out) {
  static_assert(K % 32 == 0, "K");
  __shared__ short lA[128 * 32];
  __shared__ short lB[128 * 32];
  const int t = threadIdx.x, w = t >> 6, lane = t & 63;
  const int bm0 = blockIdx.y * 128, bn0 = blockIdx.x * 128;
  const int wr = w >> 1, wc = w & 1;
  f32x4 acc[4][4] = {};
  const int srow = t >> 2, scol = (t & 3) * 8;
  const short* aP = A + (size_t)(bm0 + srow) * K + scol;
  const short* bP = B + (size_t)(bn0 + srow) * K + scol;
  short* lA0 = &lA[(w * 64) * 8];
  short* lA1 = &lA[(256 + w * 64) * 8];
  short* lB0 = &lB[(w * 64) * 8];
  short* lB1 = &lB[(256 + w * 64) * 8];
  const int lr = lane & 15, lg = (lane >> 4) * 8;

  for (int ko = 0; ko < K; ko += 32) {
    GLL16(aP + ko, lA0);
    GLL16(aP + ko + (size_t)64 * K, lA1);
    GLL16(bP + ko, lB0);
    GLL16(bP + ko + (size_t)64 * K, lB1);
    __syncthreads();
    bf16x8 af[4], bg[4];
#pragma unroll
    for (int mi = 0; mi < 4; ++mi)
      af[mi] = *(const bf16x8*)&lA[(wr * 64 + mi * 16 + lr) * 32 + lg];
#pragma unroll
    for (int ni = 0; ni < 4; ++ni)
      bg[ni] = *(const bf16x8*)&lB[(wc * 64 + ni * 16 + lr) * 32 + lg];
#pragma unroll
    for (int mi = 0; mi < 4; ++mi)
#pragma unroll
      for (int ni = 0; ni < 4; ++ni)
        acc[mi][ni] = __builtin_amdgcn_mfma_f32_16x16x32_bf16(af[mi], bg[ni],
                                                              acc[mi][ni], 0, 0, 0);
    __syncthreads();
  }

  const int lg4 = (lane >> 4) * 4;
#pragma unroll
  for (int mi = 0; mi < 4; ++mi) {
#pragma unroll
    for (int ni = 0; ni < 4; ++ni) {
      const int row = bm0 + wr * 64 + mi * 16 + lg4;
      const int col = bn0 + wc * 64 + ni * 16 + lr;
      const float bc = bias[col];
#pragma unroll
      for (int r = 0; r < 4; ++r) {
        float v = acc[mi][ni][r] + bc;
        size_t idx = (size_t)(row + r) * N + col;
        if constexpr (EPI == 1) v = 0.5f * v * (1.0f + erff(v * 0.70710678118f));
        if constexpr (EPI == 0 || EPI == 1) ((short*)out)[idx] = f2bs(v);
        else if constexpr (EPI == 2) ((float*)out)[idx] = v + resid[idx];
        else ((float*)out)[idx] = v;
      }
    }
  }
}

// ---------------------------------------------------------------- LayerNorm -> bf16
__global__ __launch_bounds__(256) void ln_fwd(const float* __restrict__ x,
                                              const float* __restrict__ g,
                                              const float* __restrict__ b,
                                              short* __restrict__ y) {
  const int row = blockIdx.x, t = threadIdx.x, w = t >> 6, lane = t & 63;
  const float4 v = ((const float4*)(x + (size_t)row * 1024))[t];
  float s = v.x + v.y + v.z + v.w;
  float ss = v.x * v.x + v.y * v.y + v.z * v.z + v.w * v.w;
#pragma unroll
  for (int m = 1; m < 64; m <<= 1) { s += __shfl_xor(s, m); ss += __shfl_xor(ss, m); }
  __shared__ float rs[4], rss[4];
  if (lane == 0) { rs[w] = s; rss[w] = ss; }
  __syncthreads();
  s = rs[0] + rs[1] + rs[2] + rs[3];
  ss = rss[0] + rss[1] + rss[2] + rss[3];
  const float mean = s * (1.f / 1024.f);
  const float var = ss * (1.f / 1024.f) - mean * mean;
  const float rstd = rsqrtf(var + 1e-6f);
  const float4 gv = ((const float4*)g)[t];
  const float4 bv = ((const float4*)b)[t];
  s16x4 o;
  o[0] = f2bs((v.x - mean) * rstd * gv.x + bv.x);
  o[1] = f2bs((v.y - mean) * rstd * gv.y + bv.y);
  o[2] = f2bs((v.z - mean) * rstd * gv.z + bv.z);
  o[3] = f2bs((v.w - mean) * rstd * gv.w + bv.w);
  *(s16x4*)(y + (size_t)row * 1024 + t * 4) = o;
}

// ---------------------------------------------------------------- pos-embed bilinear add
__global__ __launch_bounds__(256) void pos_add(float* __restrict__ x,
                                               const float* __restrict__ pe) {
  const int sidx = blockIdx.x;
  const int f = sidx & 1023;
  const int wq = 2 * ((f >> 2) & 15) + (f & 1);
  const int hq = 2 * (f >> 6) + ((f >> 1) & 1);
  const float gx = (wq + 0.5f) * 0.75f - 0.5f;
  const float gy = (hq + 0.5f) * 0.75f - 0.5f;
  const float fx = floorf(gx), fy = floorf(gy);
  const float wx = gx - fx, wy = gy - fy;
  int x0 = (int)fx, y0 = (int)fy;
  const int x0i = x0 < 0 ? 0 : (x0 > 23 ? 23 : x0);
  const int x1i = (x0 + 1) < 0 ? 0 : ((x0 + 1) > 23 ? 23 : x0 + 1);
  const int y0i = y0 < 0 ? 0 : (y0 > 23 ? 23 : y0);
  const int y1i = (y0 + 1) < 0 ? 0 : ((y0 + 1) > 23 ? 23 : y0 + 1);
  const float w00 = (1 - wy) * (1 - wx), w01 = (1 - wy) * wx;
  const float w10 = wy * (1 - wx), w11 = wy * wx;
  const int c = threadIdx.x * 4;
  const float4 p00 = *(const float4*)(pe + (size_t)(y0i * 24 + x0i) * 1024 + c);
  const float4 p01 = *(const float4*)(pe + (size_t)(y0i * 24 + x1i) * 1024 + c);
  const float4 p10 = *(const float4*)(pe + (size_t)(y1i * 24 + x0i) * 1024 + c);
  const float4 p11 = *(const float4*)(pe + (size_t)(y1i * 24 + x1i) * 1024 + c);
  float* xp = x + (size_t)sidx * 1024 + c;
  float4 xv = *(float4*)xp;
  xv.x += w00 * p00.x + w01 * p01.x + w10 * p10.x + w11 * p11.x;
  xv.y += w00 * p00.y + w01 * p01.y + w10 * p10.y + w11 * p11.y;
  xv.z += w00 * p00.z + w01 * p01.z + w10 * p10.z + w11 * p11.z;
  xv.w += w00 * p00.w + w01 * p01.w + w10 * p10.w + w11 * p11.w;
  *(float4*)xp = xv;
}

// ---------------------------------------------------------------- attention (flash, swapped)
// qkv bf16 [4096][3072] (q|k|v each [NH=16][HD=64]); out bf16 [4096][1024]
__global__ __launch_bounds__(256) void attn_fwd(const short* __restrict__ qkv,
                                                short* __restrict__ outp) {
  __shared__ short Vt[64 * 72];  // V^T tile: [d=64][kv=64], stride 72 vs bank conflicts
  const int t = threadIdx.x, w = t >> 6, lane = t & 63;
  const int b = blockIdx.y >> 4, h = blockIdx.y & 15;
  const int sbase = b * 1024;
  const int q0 = blockIdx.x * 64 + w * 16;
  const int lr = lane & 15, lg = lane >> 4;

  const short* qrow = qkv + (size_t)(sbase + q0 + lr) * 3072 + h * 64;
  const bf16x8 qf0 = *(const bf16x8*)(qrow + lg * 8);
  const bf16x8 qf1 = *(const bf16x8*)(qrow + 32 + lg * 8);

  f32x4 o[4] = {};
  float mrun = -1e30f, lsum = 0.f;

  const int vkv = t >> 2, vdp = t & 3;
  const short* vbase = qkv + 2048 + h * 64 + vdp * 16;

  for (int kb = 0; kb < 16; ++kb) {
    __syncthreads();
    {
      const short* vrow = vbase + (size_t)(sbase + kb * 64 + vkv) * 3072;
      s16x8 v0 = *(const s16x8*)vrow;
      s16x8 v1 = *(const s16x8*)(vrow + 8);
#pragma unroll
      for (int j = 0; j < 8; ++j) Vt[(vdp * 16 + j) * 72 + vkv] = v0[j];
#pragma unroll
      for (int j = 0; j < 8; ++j) Vt[(vdp * 16 + 8 + j) * 72 + vkv] = v1[j];
    }
    __syncthreads();
#pragma unroll
    for (int sub = 0; sub < 4; ++sub) {
      const int kv0 = kb * 64 + sub * 16;
      const short* krow = qkv + (size_t)(sbase + kv0 + lr) * 3072 + 1024 + h * 64;
      const bf16x8 kf0 = *(const bf16x8*)(krow + lg * 8);
      const bf16x8 kf1 = *(const bf16x8*)(krow + 32 + lg * 8);
      f32x4 s = {};
      s = __builtin_amdgcn_mfma_f32_16x16x32_bf16(kf0, qf0, s, 0, 0, 0);
      s = __builtin_amdgcn_mfma_f32_16x16x32_bf16(kf1, qf1, s, 0, 0, 0);
      const float s0 = s[0] * 0.125f, s1 = s[1] * 0.125f;
      const float s2 = s[2] * 0.125f, s3 = s[3] * 0.125f;
      float tm = fmaxf(fmaxf(s0, s1), fmaxf(s2, s3));
      tm = fmaxf(tm, __shfl_xor(tm, 16));
      tm = fmaxf(tm, __shfl_xor(tm, 32));
      const float mn = fmaxf(mrun, tm);
      const float sc = __expf(mrun - mn);
      const float p0 = __expf(s0 - mn), p1 = __expf(s1 - mn);
      const float p2 = __expf(s2 - mn), p3 = __expf(s3 - mn);
      float ps = p0 + p1 + p2 + p3;
      ps += __shfl_xor(ps, 16);
      ps += __shfl_xor(ps, 32);
      lsum = lsum * sc + ps;
      mrun = mn;
      s16x4 pb;
      pb[0] = f2bs(p0); pb[1] = f2bs(p1); pb[2] = f2bs(p2); pb[3] = f2bs(p3);
#pragma unroll
      for (int f = 0; f < 4; ++f) {
        o[f][0] *= sc; o[f][1] *= sc; o[f][2] *= sc; o[f][3] *= sc;
        const s16x4 va = *(const s16x4*)&Vt[(f * 16 + lr) * 72 + sub * 16 + lg * 4];
        o[f] = __builtin_amdgcn_mfma_f32_16x16x16bf16_1k(va, pb, o[f], 0, 0, 0);
      }
    }
  }
  const float inv = 1.0f / lsum;
  short* orow = outp + (size_t)(sbase + q0 + lr) * 1024 + h * 64;
#pragma unroll
  for (int f = 0; f < 4; ++f) {
    s16x4 ov;
    ov[0] = f2bs(o[f][0] * inv); ov[1] = f2bs(o[f][1] * inv);
    ov[2] = f2bs(o[f][2] * inv); ov[3] = f2bs(o[f][3] * inv);
    *(s16x4*)(orow + f * 16 + lg * 4) = ov;
  }
}

// ---------------------------------------------------------------- launch
extern "C" void kernel_launch(void* const* d_in, const int* in_sizes, int n_in,
                              void* d_out, int out_size, void* d_ws, size_t ws_size,
                              hipStream_t stream) {
  const float* pixel  = (const float*)d_in[0];
  const float* conv_w = (const float*)d_in[2];
  const float* conv_b = (const float*)d_in[3];
  const float* pos_e  = (const float*)d_in[4];
  const float* ln1_g  = (const float*)d_in[5];
  const float* ln1_b  = (const float*)d_in[6];
  const float* qkv_w  = (const float*)d_in[7];
  const float* qkv_b  = (const float*)d_in[8];
  const float* proj_w = (const float*)d_in[9];
  const float* proj_b = (const float*)d_in[10];
  const float* ln2_g  = (const float*)d_in[11];
  const float* ln2_b  = (const float*)d_in[12];
  const float* fc1_w  = (const float*)d_in[13];
  const float* fc1_b  = (const float*)d_in[14];
  const float* fc2_w  = (const float*)d_in[15];
  const float* fc2_b  = (const float*)d_in[16];

  char* ws = (char*)d_ws;
  short* wQKV  = (short*)(ws + 0);           // 25165824
  short* wPROJ = (short*)(ws + 25165824);    // 8388608
  short* wFC1  = (short*)(ws + 33554432);    // 33554432
  short* wFC2  = (short*)(ws + 67108864);    // 33554432
  float* X     = (float*)(ws + 100663296);   // 16777216
  short* Y     = (short*)(ws + 117440512);   // 8388608
  short* QKVB  = (short*)(ws + 125829120);   // 25165824
  short* ATTNO = (short*)(ws + 150994944);   // 8388608  (end 159383552)
  short* H     = QKVB;                       // alias (33554432 = QKVB+ATTNO exactly)
  short* WPIX  = QKVB;                       // alias, used only before layer 0
  short* WCONV = (short*)(ws + 125829120 + 4980736);

  cvt_f32_bf16<<<2048, 256, 0, stream>>>(qkv_w, wQKV, 4 * 3072 * 1024);
  cvt_f32_bf16<<<1024, 256, 0, stream>>>(proj_w, wPROJ, 4 * 1024 * 1024);
  cvt_f32_bf16<<<2048, 256, 0, stream>>>(fc1_w, wFC1, 4 * 4096 * 1024);
  cvt_f32_bf16<<<2048, 256, 0, stream>>>(fc2_w, wFC2, 4 * 1024 * 4096);
  cvt_pad<<<4096, 256, 0, stream>>>(pixel, WPIX);
  cvt_pad<<<1024, 256, 0, stream>>>(conv_w, WCONV);

  gemm_bt<1024, 608, 3><<<dim3(8, 32), 256, 0, stream>>>(WPIX, WCONV, conv_b, nullptr, X);
  pos_add<<<4096, 256, 0, stream>>>(X, pos_e);

  for (int i = 0; i < 4; ++i) {
    ln_fwd<<<4096, 256, 0, stream>>>(X, ln1_g + i * 1024, ln1_b + i * 1024, Y);
    gemm_bt<3072, 1024, 0><<<dim3(24, 32), 256, 0, stream>>>(
        Y, wQKV + (size_t)i * 3072 * 1024, qkv_b + i * 3072, nullptr, QKVB);
    attn_fwd<<<dim3(16, 64), 256, 0, stream>>>(QKVB, ATTNO);
    gemm_bt<1024, 1024, 2><<<dim3(8, 32), 256, 0, stream>>>(
        ATTNO, wPROJ + (size_t)i * 1024 * 1024, proj_b + i * 1024, X, X);
    ln_fwd<<<4096, 256, 0, stream>>>(X, ln2_g + i * 1024, ln2_b + i * 1024, Y);
    gemm_bt<4096, 1024, 1><<<dim3(32, 32), 256, 0, stream>>>(
        Y, wFC1 + (size_t)i * 4096 * 1024, fc1_b + i * 4096, nullptr, H);
    float* dest = (i < 3) ? X : (float*)d_out;
    gemm_bt<1024, 4096, 2><<<dim3(8, 32), 256, 0, stream>>>(
        H, wFC2 + (size_t)i * 1024 * 4096, fc2_b + i * 1024, X, dest);
  }
}

// Round 2
// 1349.532 us; speedup vs baseline: 1.0063x; 1.0063x over previous
//
#include <hip/hip_runtime.h>
#include <math.h>

typedef __bf16 bf16x8 __attribute__((ext_vector_type(8)));
typedef float f32x4 __attribute__((ext_vector_type(4)));
typedef short s16x4 __attribute__((ext_vector_type(4)));
typedef short s16x8 __attribute__((ext_vector_type(8)));

static __device__ __forceinline__ short f2bs(float f) {
  return __builtin_bit_cast(short, (__bf16)f);
}

#define GLL16(gp, lp) __builtin_amdgcn_global_load_lds( \
    (const __attribute__((address_space(1))) void*)(gp), \
    (__attribute__((address_space(3))) void*)(lp), 16, 0, 0)

// ---------------------------------------------------------------- conversions
__global__ __launch_bounds__(256) void cvt_f32_bf16(const float* __restrict__ s,
                                                    short* __restrict__ d, int n) {
  int stride = gridDim.x * blockDim.x * 4;
  for (int j = (blockIdx.x * blockDim.x + threadIdx.x) * 4; j < n; j += stride) {
    float4 v = *(const float4*)(s + j);
    s16x4 o;
    o[0] = f2bs(v.x); o[1] = f2bs(v.y); o[2] = f2bs(v.z); o[3] = f2bs(v.w);
    *(s16x4*)(d + j) = o;
  }
}

// pad K 588 -> 608 with zeros, row-major
__global__ __launch_bounds__(256) void cvt_pad(const float* __restrict__ s,
                                               short* __restrict__ d) {
  int r = blockIdx.x;
  for (int c = threadIdx.x; c < 608; c += blockDim.x)
    d[(size_t)r * 608 + c] = (c < 588) ? f2bs(s[(size_t)r * 588 + c]) : (short)0;
}

// ---------------------------------------------------------------- GEMM
// C[M=4096,N] = A[M,K](bf16) @ B[N,K](bf16)^T + bias, epilogue variants.
// EPI: 0 = bf16 out, 1 = bf16 + exact GELU, 2 = f32 + residual, 3 = f32
// 2-phase pipeline: stage(next) -> compute(cur) -> 1 barrier (drains vmcnt).
// XCD swizzle: chunk of nwg/8 consecutive work-ids per XCD, shaped CMxCN cells.
// LDS swizzle: physical colblock q = logical ^ ((row>>1)&3), both sides (rule 21).
template <int N, int K, int EPI, int CM, int CN>
__global__ __launch_bounds__(256) void gemm_bt(const short* __restrict__ A,
                                               const short* __restrict__ B,
                                               const float* __restrict__ bias,
                                               const float* __restrict__ resid,
                                               void* __restrict__ out) {
  static_assert(K % 32 == 0, "K");
  constexpr int NX = N / 128, NY = 32;
  constexpr int nwg = NX * NY;
  static_assert(nwg % 8 == 0 && (nwg / 8) % (CM * CN) == 0, "chunk");
  static_assert(NX % CN == 0 && NY % CM == 0, "cells");
  __shared__ short lA[2][128 * 32];
  __shared__ short lB[2][128 * 32];

  // block swizzle: XCD-contiguous chunks of compact CMxCN cells
  const int o = blockIdx.x;
  const int wid = (o & 7) * (nwg / 8) + (o >> 3);
  constexpr int cellsz = CM * CN;
  const int cell = wid / cellsz, within = wid % cellsz;
  constexpr int cellsx = NX / CN;
  const int bm0 = ((cell / cellsx) * CM + within / CN) * 128;
  const int bn0 = ((cell % cellsx) * CN + within % CN) * 128;

  const int t = threadIdx.x, w = t >> 6, lane = t & 63;
  const int wr = w >> 1, wc = w & 1;
  f32x4 acc[4][4] = {};

  // staging addresses (source column pre-swizzled for bank-conflict-free reads)
  const int srow = t >> 2;
  const int scol = ((t & 3) ^ ((srow >> 1) & 3)) * 8;
  const short* aP = A + (size_t)(bm0 + srow) * K + scol;
  const short* bP = B + (size_t)(bn0 + srow) * K + scol;
  const int sdst0 = (w * 16) * 32;        // wave's 16 rows (chunk 0)
  const int sdst1 = (64 + w * 16) * 32;   // chunk 1 (+64 rows)

  const int lr = lane & 15;
  const int qx = ((lane >> 4) ^ ((lr >> 1) & 3)) * 8;  // swizzled read col

  auto stage = [&](int buf, int ko) {
    GLL16(aP + ko, &lA[buf][sdst0]);
    GLL16(aP + ko + (size_t)64 * K, &lA[buf][sdst1]);
    GLL16(bP + ko, &lB[buf][sdst0]);
    GLL16(bP + ko + (size_t)64 * K, &lB[buf][sdst1]);
  };
  auto compute = [&](int buf) {
    bf16x8 af[4], bg[4];
#pragma unroll
    for (int mi = 0; mi < 4; ++mi)
      af[mi] = *(const bf16x8*)&lA[buf][(wr * 64 + mi * 16 + lr) * 32 + qx];
#pragma unroll
    for (int ni = 0; ni < 4; ++ni)
      bg[ni] = *(const bf16x8*)&lB[buf][(wc * 64 + ni * 16 + lr) * 32 + qx];
#pragma unroll
    for (int mi = 0; mi < 4; ++mi)
#pragma unroll
      for (int ni = 0; ni < 4; ++ni)
        acc[mi][ni] = __builtin_amdgcn_mfma_f32_16x16x32_bf16(af[mi], bg[ni],
                                                              acc[mi][ni], 0, 0, 0);
  };

  stage(0, 0);
  __syncthreads();
  int cur = 0;
  for (int ko = 32; ko < K; ko += 32) {
    stage(cur ^ 1, ko);
    compute(cur);
    __syncthreads();   // drains vmcnt(0): next tile ready; lgkm: reads done
    cur ^= 1;
  }
  compute(cur);

  const int lg4 = (lane >> 4) * 4;
#pragma unroll
  for (int mi = 0; mi < 4; ++mi) {
#pragma unroll
    for (int ni = 0; ni < 4; ++ni) {
      const int row = bm0 + wr * 64 + mi * 16 + lg4;
      const int col = bn0 + wc * 64 + ni * 16 + lr;
      const float bc = bias[col];
#pragma unroll
      for (int r = 0; r < 4; ++r) {
        float v = acc[mi][ni][r] + bc;
        size_t idx = (size_t)(row + r) * N + col;
        if constexpr (EPI == 1) v = 0.5f * v * (1.0f + erff(v * 0.70710678118f));
        if constexpr (EPI == 0 || EPI == 1) ((short*)out)[idx] = f2bs(v);
        else if constexpr (EPI == 2) ((float*)out)[idx] = v + resid[idx];
        else ((float*)out)[idx] = v;
      }
    }
  }
}

// ---------------------------------------------------------------- LayerNorm -> bf16
__global__ __launch_bounds__(256) void ln_fwd(const float* __restrict__ x,
                                              const float* __restrict__ g,
                                              const float* __restrict__ b,
                                              short* __restrict__ y) {
  const int row = blockIdx.x, t = threadIdx.x, w = t >> 6, lane = t & 63;
  const float4 v = ((const float4*)(x + (size_t)row * 1024))[t];
  float s = v.x + v.y + v.z + v.w;
  float ss = v.x * v.x + v.y * v.y + v.z * v.z + v.w * v.w;
#pragma unroll
  for (int m = 1; m < 64; m <<= 1) { s += __shfl_xor(s, m); ss += __shfl_xor(ss, m); }
  __shared__ float rs[4], rss[4];
  if (lane == 0) { rs[w] = s; rss[w] = ss; }
  __syncthreads();
  s = rs[0] + rs[1] + rs[2] + rs[3];
  ss = rss[0] + rss[1] + rss[2] + rss[3];
  const float mean = s * (1.f / 1024.f);
  const float var = ss * (1.f / 1024.f) - mean * mean;
  const float rstd = rsqrtf(var + 1e-6f);
  const float4 gv = ((const float4*)g)[t];
  const float4 bv = ((const float4*)b)[t];
  s16x4 o;
  o[0] = f2bs((v.x - mean) * rstd * gv.x + bv.x);
  o[1] = f2bs((v.y - mean) * rstd * gv.y + bv.y);
  o[2] = f2bs((v.z - mean) * rstd * gv.z + bv.z);
  o[3] = f2bs((v.w - mean) * rstd * gv.w + bv.w);
  *(s16x4*)(y + (size_t)row * 1024 + t * 4) = o;
}

// ---------------------------------------------------------------- pos-embed bilinear add
__global__ __launch_bounds__(256) void pos_add(float* __restrict__ x,
                                               const float* __restrict__ pe) {
  const int sidx = blockIdx.x;
  const int f = sidx & 1023;
  const int wq = 2 * ((f >> 2) & 15) + (f & 1);
  const int hq = 2 * (f >> 6) + ((f >> 1) & 1);
  const float gx = (wq + 0.5f) * 0.75f - 0.5f;
  const float gy = (hq + 0.5f) * 0.75f - 0.5f;
  const float fx = floorf(gx), fy = floorf(gy);
  const float wx = gx - fx, wy = gy - fy;
  int x0 = (int)fx, y0 = (int)fy;
  const int x0i = x0 < 0 ? 0 : (x0 > 23 ? 23 : x0);
  const int x1i = (x0 + 1) < 0 ? 0 : ((x0 + 1) > 23 ? 23 : x0 + 1);
  const int y0i = y0 < 0 ? 0 : (y0 > 23 ? 23 : y0);
  const int y1i = (y0 + 1) < 0 ? 0 : ((y0 + 1) > 23 ? 23 : y0 + 1);
  const float w00 = (1 - wy) * (1 - wx), w01 = (1 - wy) * wx;
  const float w10 = wy * (1 - wx), w11 = wy * wx;
  const int c = threadIdx.x * 4;
  const float4 p00 = *(const float4*)(pe + (size_t)(y0i * 24 + x0i) * 1024 + c);
  const float4 p01 = *(const float4*)(pe + (size_t)(y0i * 24 + x1i) * 1024 + c);
  const float4 p10 = *(const float4*)(pe + (size_t)(y1i * 24 + x0i) * 1024 + c);
  const float4 p11 = *(const float4*)(pe + (size_t)(y1i * 24 + x1i) * 1024 + c);
  float* xp = x + (size_t)sidx * 1024 + c;
  float4 xv = *(float4*)xp;
  xv.x += w00 * p00.x + w01 * p01.x + w10 * p10.x + w11 * p11.x;
  xv.y += w00 * p00.y + w01 * p01.y + w10 * p10.y + w11 * p11.y;
  xv.z += w00 * p00.z + w01 * p01.z + w10 * p10.z + w11 * p11.z;
  xv.w += w00 * p00.w + w01 * p01.w + w10 * p10.w + w11 * p11.w;
  *(float4*)xp = xv;
}

// ---------------------------------------------------------------- attention (flash, swapped)
// qkv bf16 [4096][3072] (q|k|v each [NH=16][HD=64]); out bf16 [4096][1024]
__global__ __launch_bounds__(256) void attn_fwd(const short* __restrict__ qkv,
                                                short* __restrict__ outp) {
  __shared__ short Vt[64 * 72];  // V^T tile: [d=64][kv=64], stride 72 vs bank conflicts
  const int t = threadIdx.x, w = t >> 6, lane = t & 63;
  const int b = blockIdx.y >> 4, h = blockIdx.y & 15;
  const int sbase = b * 1024;
  const int q0 = blockIdx.x * 64 + w * 16;
  const int lr = lane & 15, lg = lane >> 4;

  const short* qrow = qkv + (size_t)(sbase + q0 + lr) * 3072 + h * 64;
  const bf16x8 qf0 = *(const bf16x8*)(qrow + lg * 8);
  const bf16x8 qf1 = *(const bf16x8*)(qrow + 32 + lg * 8);

  f32x4 o[4] = {};
  float mrun = -1e30f, lsum = 0.f;

  const int vkv = t >> 2, vdp = t & 3;
  const short* vbase = qkv + 2048 + h * 64 + vdp * 16;

  for (int kb = 0; kb < 16; ++kb) {
    __syncthreads();
    {
      const short* vrow = vbase + (size_t)(sbase + kb * 64 + vkv) * 3072;
      s16x8 v0 = *(const s16x8*)vrow;
      s16x8 v1 = *(const s16x8*)(vrow + 8);
#pragma unroll
      for (int j = 0; j < 8; ++j) Vt[(vdp * 16 + j) * 72 + vkv] = v0[j];
#pragma unroll
      for (int j = 0; j < 8; ++j) Vt[(vdp * 16 + 8 + j) * 72 + vkv] = v1[j];
    }
    __syncthreads();
#pragma unroll
    for (int sub = 0; sub < 4; ++sub) {
      const int kv0 = kb * 64 + sub * 16;
      const short* krow = qkv + (size_t)(sbase + kv0 + lr) * 3072 + 1024 + h * 64;
      const bf16x8 kf0 = *(const bf16x8*)(krow + lg * 8);
      const bf16x8 kf1 = *(const bf16x8*)(krow + 32 + lg * 8);
      f32x4 s = {};
      s = __builtin_amdgcn_mfma_f32_16x16x32_bf16(kf0, qf0, s, 0, 0, 0);
      s = __builtin_amdgcn_mfma_f32_16x16x32_bf16(kf1, qf1, s, 0, 0, 0);
      const float s0 = s[0] * 0.125f, s1 = s[1] * 0.125f;
      const float s2 = s[2] * 0.125f, s3 = s[3] * 0.125f;
      float tm = fmaxf(fmaxf(s0, s1), fmaxf(s2, s3));
      tm = fmaxf(tm, __shfl_xor(tm, 16));
      tm = fmaxf(tm, __shfl_xor(tm, 32));
      const float mn = fmaxf(mrun, tm);
      const float sc = __expf(mrun - mn);
      const float p0 = __expf(s0 - mn), p1 = __expf(s1 - mn);
      const float p2 = __expf(s2 - mn), p3 = __expf(s3 - mn);
      float ps = p0 + p1 + p2 + p3;
      ps += __shfl_xor(ps, 16);
      ps += __shfl_xor(ps, 32);
      lsum = lsum * sc + ps;
      mrun = mn;
      s16x4 pb;
      pb[0] = f2bs(p0); pb[1] = f2bs(p1); pb[2] = f2bs(p2); pb[3] = f2bs(p3);
#pragma unroll
      for (int f = 0; f < 4; ++f) {
        o[f][0] *= sc; o[f][1] *= sc; o[f][2] *= sc; o[f][3] *= sc;
        const s16x4 va = *(const s16x4*)&Vt[(f * 16 + lr) * 72 + sub * 16 + lg * 4];
        o[f] = __builtin_amdgcn_mfma_f32_16x16x16bf16_1k(va, pb, o[f], 0, 0, 0);
      }
    }
  }
  const float inv = 1.0f / lsum;
  short* orow = outp + (size_t)(sbase + q0 + lr) * 1024 + h * 64;
#pragma unroll
  for (int f = 0; f < 4; ++f) {
    s16x4 ov;
    ov[0] = f2bs(o[f][0] * inv); ov[1] = f2bs(o[f][1] * inv);
    ov[2] = f2bs(o[f][2] * inv); ov[3] = f2bs(o[f][3] * inv);
    *(s16x4*)(orow + f * 16 + lg * 4) = ov;
  }
}

// ---------------------------------------------------------------- launch
extern "C" void kernel_launch(void* const* d_in, const int* in_sizes, int n_in,
                              void* d_out, int out_size, void* d_ws, size_t ws_size,
                              hipStream_t stream) {
  const float* pixel  = (const float*)d_in[0];
  const float* conv_w = (const float*)d_in[2];
  const float* conv_b = (const float*)d_in[3];
  const float* pos_e  = (const float*)d_in[4];
  const float* ln1_g  = (const float*)d_in[5];
  const float* ln1_b  = (const float*)d_in[6];
  const float* qkv_w  = (const float*)d_in[7];
  const float* qkv_b  = (const float*)d_in[8];
  const float* proj_w = (const float*)d_in[9];
  const float* proj_b = (const float*)d_in[10];
  const float* ln2_g  = (const float*)d_in[11];
  const float* ln2_b  = (const float*)d_in[12];
  const float* fc1_w  = (const float*)d_in[13];
  const float* fc1_b  = (const float*)d_in[14];
  const float* fc2_w  = (const float*)d_in[15];
  const float* fc2_b  = (const float*)d_in[16];

  char* ws = (char*)d_ws;
  short* wQKV  = (short*)(ws + 0);           // 25165824
  short* wPROJ = (short*)(ws + 25165824);    // 8388608
  short* wFC1  = (short*)(ws + 33554432);    // 33554432
  short* wFC2  = (short*)(ws + 67108864);    // 33554432
  float* X     = (float*)(ws + 100663296);   // 16777216
  short* Y     = (short*)(ws + 117440512);   // 8388608
  short* QKVB  = (short*)(ws + 125829120);   // 25165824
  short* ATTNO = (short*)(ws + 150994944);   // 8388608  (end 159383552)
  short* H     = QKVB;                       // alias (33554432 = QKVB+ATTNO exactly)
  short* WPIX  = QKVB;                       // alias, used only before layer 0
  short* WCONV = (short*)(ws + 125829120 + 4980736);

  cvt_f32_bf16<<<2048, 256, 0, stream>>>(qkv_w, wQKV, 4 * 3072 * 1024);
  cvt_f32_bf16<<<1024, 256, 0, stream>>>(proj_w, wPROJ, 4 * 1024 * 1024);
  cvt_f32_bf16<<<2048, 256, 0, stream>>>(fc1_w, wFC1, 4 * 4096 * 1024);
  cvt_f32_bf16<<<2048, 256, 0, stream>>>(fc2_w, wFC2, 4 * 1024 * 4096);
  cvt_pad<<<4096, 256, 0, stream>>>(pixel, WPIX);
  cvt_pad<<<1024, 256, 0, stream>>>(conv_w, WCONV);

  gemm_bt<1024, 608, 3, 4, 8><<<256, 256, 0, stream>>>(WPIX, WCONV, conv_b, nullptr, X);
  pos_add<<<4096, 256, 0, stream>>>(X, pos_e);

  for (int i = 0; i < 4; ++i) {
    ln_fwd<<<4096, 256, 0, stream>>>(X, ln1_g + i * 1024, ln1_b + i * 1024, Y);
    gemm_bt<3072, 1024, 0, 8, 12><<<768, 256, 0, stream>>>(
        Y, wQKV + (size_t)i * 3072 * 1024, qkv_b + i * 3072, nullptr, QKVB);
    attn_fwd<<<dim3(16, 64), 256, 0, stream>>>(QKVB, ATTNO);
    gemm_bt<1024, 1024, 2, 4, 8><<<256, 256, 0, stream>>>(
        ATTNO, wPROJ + (size_t)i * 1024 * 1024, proj_b + i * 1024, X, X);
    ln_fwd<<<4096, 256, 0, stream>>>(X, ln2_g + i * 1024, ln2_b + i * 1024, Y);
    gemm_bt<4096, 1024, 1, 16, 8><<<1024, 256, 0, stream>>>(
        Y, wFC1 + (size_t)i * 4096 * 1024, fc1_b + i * 4096, nullptr, H);
    float* dest = (i < 3) ? X : (float*)d_out;
    gemm_bt<1024, 4096, 2, 4, 8><<<256, 256, 0, stream>>>(
        H, wFC2 + (size_t)i * 1024 * 4096, fc2_b + i * 1024, X, dest);
  }
}

// Round 3
// 1171.404 us; speedup vs baseline: 1.1593x; 1.1521x over previous
//
#include <hip/hip_runtime.h>
#include <math.h>

typedef __bf16 bf16x8 __attribute__((ext_vector_type(8)));
typedef float f32x4 __attribute__((ext_vector_type(4)));
typedef short s16x4 __attribute__((ext_vector_type(4)));
typedef short s16x8 __attribute__((ext_vector_type(8)));

static __device__ __forceinline__ short f2bs(float f) {
  return __builtin_bit_cast(short, (__bf16)f);
}

#define GLL16(gp, lp) __builtin_amdgcn_global_load_lds( \
    (const __attribute__((address_space(1))) void*)(gp), \
    (__attribute__((address_space(3))) void*)(lp), 16, 0, 0)

// ---------------------------------------------------------------- conversions
__global__ __launch_bounds__(256) void cvt_f32_bf16(const float* __restrict__ s,
                                                    short* __restrict__ d, int n) {
  int stride = gridDim.x * blockDim.x * 4;
  for (int j = (blockIdx.x * blockDim.x + threadIdx.x) * 4; j < n; j += stride) {
    float4 v = *(const float4*)(s + j);
    s16x4 o;
    o[0] = f2bs(v.x); o[1] = f2bs(v.y); o[2] = f2bs(v.z); o[3] = f2bs(v.w);
    *(s16x4*)(d + j) = o;
  }
}

// pad K 588 -> 608 with zeros, row-major
__global__ __launch_bounds__(256) void cvt_pad(const float* __restrict__ s,
                                               short* __restrict__ d) {
  int r = blockIdx.x;
  for (int c = threadIdx.x; c < 608; c += blockDim.x)
    d[(size_t)r * 608 + c] = (c < 588) ? f2bs(s[(size_t)r * 588 + c]) : (short)0;
}

// ---------------------------------------------------------------- GEMM
// C[M=4096,N] = A[M,K](bf16) @ B[N,K](bf16)^T + bias, epilogue variants.
// EPI: 0 = bf16 out, 1 = bf16 + exact GELU, 2 = f32 + residual, 3 = f32
// 3-deep prefetch pipeline, counted vmcnt (T3+T4): per K-step
//   vmcnt(8) -> barrier -> ds_read -> lgkmcnt(0) -> barrier -> stage(t+3) -> MFMA
// vmcnt never drains to 0 in steady state; loads span ~3 iters of latency.
// XCD swizzle: chunk of nwg/8 consecutive work-ids per XCD, shaped CMxCN cells.
// LDS swizzle: physical colblock q = logical ^ ((row>>1)&3), both sides (rule 21).
template <int N, int K, int EPI, int CM, int CN>
__global__ __launch_bounds__(256) void gemm_bt(const short* __restrict__ A,
                                               const short* __restrict__ B,
                                               const float* __restrict__ bias,
                                               const float* __restrict__ resid,
                                               void* __restrict__ out) {
  static_assert(K % 32 == 0, "K");
  constexpr int NT = K / 32;
  static_assert(NT >= 3, "pipeline depth");
  constexpr int NX = N / 128, NY = 32;
  constexpr int nwg = NX * NY;
  static_assert(nwg % 8 == 0 && (nwg / 8) % (CM * CN) == 0, "chunk");
  static_assert(NX % CN == 0 && NY % CM == 0, "cells");
  __shared__ short lA[3][128 * 32];
  __shared__ short lB[3][128 * 32];

  // block swizzle: XCD-contiguous chunks of compact CMxCN cells
  const int o = blockIdx.x;
  const int wid = (o & 7) * (nwg / 8) + (o >> 3);
  constexpr int cellsz = CM * CN;
  const int cell = wid / cellsz, within = wid % cellsz;
  constexpr int cellsx = NX / CN;
  const int bm0 = ((cell / cellsx) * CM + within / CN) * 128;
  const int bn0 = ((cell % cellsx) * CN + within % CN) * 128;

  const int t = threadIdx.x, w = t >> 6, lane = t & 63;
  const int wr = w >> 1, wc = w & 1;
  f32x4 acc[4][4] = {};

  // staging addresses (source column pre-swizzled for bank-conflict-free reads)
  const int srow = t >> 2;
  const int scol = ((t & 3) ^ ((srow >> 1) & 3)) * 8;
  const short* aP = A + (size_t)(bm0 + srow) * K + scol;
  const short* bP = B + (size_t)(bn0 + srow) * K + scol;
  const int sdst0 = (w * 16) * 32;        // wave's 16 rows (chunk 0)
  const int sdst1 = (64 + w * 16) * 32;   // chunk 1 (+64 rows)

  const int lr = lane & 15;
  const int qx = ((lane >> 4) ^ ((lr >> 1) & 3)) * 8;  // swizzled read col

  auto stage = [&](int buf, int ko) {
    GLL16(aP + ko, &lA[buf][sdst0]);
    GLL16(aP + ko + (size_t)64 * K, &lA[buf][sdst1]);
    GLL16(bP + ko, &lB[buf][sdst0]);
    GLL16(bP + ko + (size_t)64 * K, &lB[buf][sdst1]);
  };

  stage(0, 0);
  stage(1, 32);
  stage(2, 64);

  int buf = 0;
  for (int kt = 0; kt < NT; ++kt) {
    // wait for tile kt's 4 loads (per-wave in-order retirement); keep rest in flight
    if (kt < NT - 2)       asm volatile("s_waitcnt vmcnt(8)" ::: "memory");
    else if (kt == NT - 2) asm volatile("s_waitcnt vmcnt(4)" ::: "memory");
    else                   asm volatile("s_waitcnt vmcnt(0)" ::: "memory");
    __builtin_amdgcn_s_barrier();           // all waves' tile-kt loads landed
    asm volatile("" ::: "memory");
    __builtin_amdgcn_sched_barrier(0);

    bf16x8 af[4], bg[4];
#pragma unroll
    for (int mi = 0; mi < 4; ++mi)
      af[mi] = *(const bf16x8*)&lA[buf][(wr * 64 + mi * 16 + lr) * 32 + qx];
#pragma unroll
    for (int ni = 0; ni < 4; ++ni)
      bg[ni] = *(const bf16x8*)&lB[buf][(wc * 64 + ni * 16 + lr) * 32 + qx];

    asm volatile("s_waitcnt lgkmcnt(0)" ::: "memory");  // this wave's reads done
    __builtin_amdgcn_sched_barrier(0);
    __builtin_amdgcn_s_barrier();           // all waves done reading buf -> free
    asm volatile("" ::: "memory");
    __builtin_amdgcn_sched_barrier(0);

    if (kt + 3 < NT) stage(buf, (kt + 3) * 32);  // refill freed buffer
    __builtin_amdgcn_sched_barrier(0);           // issue loads before MFMA cluster

#pragma unroll
    for (int mi = 0; mi < 4; ++mi)
#pragma unroll
      for (int ni = 0; ni < 4; ++ni)
        acc[mi][ni] = __builtin_amdgcn_mfma_f32_16x16x32_bf16(af[mi], bg[ni],
                                                              acc[mi][ni], 0, 0, 0);
    buf = (buf == 2) ? 0 : buf + 1;
  }

  const int lg4 = (lane >> 4) * 4;
#pragma unroll
  for (int mi = 0; mi < 4; ++mi) {
#pragma unroll
    for (int ni = 0; ni < 4; ++ni) {
      const int row = bm0 + wr * 64 + mi * 16 + lg4;
      const int col = bn0 + wc * 64 + ni * 16 + lr;
      const float bc = bias[col];
#pragma unroll
      for (int r = 0; r < 4; ++r) {
        float v = acc[mi][ni][r] + bc;
        size_t idx = (size_t)(row + r) * N + col;
        if constexpr (EPI == 1) v = 0.5f * v * (1.0f + erff(v * 0.70710678118f));
        if constexpr (EPI == 0 || EPI == 1) ((short*)out)[idx] = f2bs(v);
        else if constexpr (EPI == 2) ((float*)out)[idx] = v + resid[idx];
        else ((float*)out)[idx] = v;
      }
    }
  }
}

// ---------------------------------------------------------------- LayerNorm -> bf16
__global__ __launch_bounds__(256) void ln_fwd(const float* __restrict__ x,
                                              const float* __restrict__ g,
                                              const float* __restrict__ b,
                                              short* __restrict__ y) {
  const int row = blockIdx.x, t = threadIdx.x, w = t >> 6, lane = t & 63;
  const float4 v = ((const float4*)(x + (size_t)row * 1024))[t];
  float s = v.x + v.y + v.z + v.w;
  float ss = v.x * v.x + v.y * v.y + v.z * v.z + v.w * v.w;
#pragma unroll
  for (int m = 1; m < 64; m <<= 1) { s += __shfl_xor(s, m); ss += __shfl_xor(ss, m); }
  __shared__ float rs[4], rss[4];
  if (lane == 0) { rs[w] = s; rss[w] = ss; }
  __syncthreads();
  s = rs[0] + rs[1] + rs[2] + rs[3];
  ss = rss[0] + rss[1] + rss[2] + rss[3];
  const float mean = s * (1.f / 1024.f);
  const float var = ss * (1.f / 1024.f) - mean * mean;
  const float rstd = rsqrtf(var + 1e-6f);
  const float4 gv = ((const float4*)g)[t];
  const float4 bv = ((const float4*)b)[t];
  s16x4 o;
  o[0] = f2bs((v.x - mean) * rstd * gv.x + bv.x);
  o[1] = f2bs((v.y - mean) * rstd * gv.y + bv.y);
  o[2] = f2bs((v.z - mean) * rstd * gv.z + bv.z);
  o[3] = f2bs((v.w - mean) * rstd * gv.w + bv.w);
  *(s16x4*)(y + (size_t)row * 1024 + t * 4) = o;
}

// ---------------------------------------------------------------- pos-embed bilinear add
__global__ __launch_bounds__(256) void pos_add(float* __restrict__ x,
                                               const float* __restrict__ pe) {
  const int sidx = blockIdx.x;
  const int f = sidx & 1023;
  const int wq = 2 * ((f >> 2) & 15) + (f & 1);
  const int hq = 2 * (f >> 6) + ((f >> 1) & 1);
  const float gx = (wq + 0.5f) * 0.75f - 0.5f;
  const float gy = (hq + 0.5f) * 0.75f - 0.5f;
  const float fx = floorf(gx), fy = floorf(gy);
  const float wx = gx - fx, wy = gy - fy;
  int x0 = (int)fx, y0 = (int)fy;
  const int x0i = x0 < 0 ? 0 : (x0 > 23 ? 23 : x0);
  const int x1i = (x0 + 1) < 0 ? 0 : ((x0 + 1) > 23 ? 23 : x0 + 1);
  const int y0i = y0 < 0 ? 0 : (y0 > 23 ? 23 : y0);
  const int y1i = (y0 + 1) < 0 ? 0 : ((y0 + 1) > 23 ? 23 : y0 + 1);
  const float w00 = (1 - wy) * (1 - wx), w01 = (1 - wy) * wx;
  const float w10 = wy * (1 - wx), w11 = wy * wx;
  const int c = threadIdx.x * 4;
  const float4 p00 = *(const float4*)(pe + (size_t)(y0i * 24 + x0i) * 1024 + c);
  const float4 p01 = *(const float4*)(pe + (size_t)(y0i * 24 + x1i) * 1024 + c);
  const float4 p10 = *(const float4*)(pe + (size_t)(y1i * 24 + x0i) * 1024 + c);
  const float4 p11 = *(const float4*)(pe + (size_t)(y1i * 24 + x1i) * 1024 + c);
  float* xp = x + (size_t)sidx * 1024 + c;
  float4 xv = *(float4*)xp;
  xv.x += w00 * p00.x + w01 * p01.x + w10 * p10.x + w11 * p11.x;
  xv.y += w00 * p00.y + w01 * p01.y + w10 * p10.y + w11 * p11.y;
  xv.z += w00 * p00.z + w01 * p01.z + w10 * p10.z + w11 * p11.z;
  xv.w += w00 * p00.w + w01 * p01.w + w10 * p10.w + w11 * p11.w;
  *(float4*)xp = xv;
}

// ---------------------------------------------------------------- attention (flash, swapped)
// qkv bf16 [4096][3072] (q|k|v each [NH=16][HD=64]); out bf16 [4096][1024]
__global__ __launch_bounds__(256) void attn_fwd(const short* __restrict__ qkv,
                                                short* __restrict__ outp) {
  __shared__ short Vt[64 * 72];  // V^T tile: [d=64][kv=64], stride 72 vs bank conflicts
  const int t = threadIdx.x, w = t >> 6, lane = t & 63;
  const int b = blockIdx.y >> 4, h = blockIdx.y & 15;
  const int sbase = b * 1024;
  const int q0 = blockIdx.x * 64 + w * 16;
  const int lr = lane & 15, lg = lane >> 4;

  const short* qrow = qkv + (size_t)(sbase + q0 + lr) * 3072 + h * 64;
  const bf16x8 qf0 = *(const bf16x8*)(qrow + lg * 8);
  const bf16x8 qf1 = *(const bf16x8*)(qrow + 32 + lg * 8);

  f32x4 o[4] = {};
  float mrun = -1e30f, lsum = 0.f;

  const int vkv = t >> 2, vdp = t & 3;
  const short* vbase = qkv + 2048 + h * 64 + vdp * 16;

  for (int kb = 0; kb < 16; ++kb) {
    __syncthreads();
    {
      const short* vrow = vbase + (size_t)(sbase + kb * 64 + vkv) * 3072;
      s16x8 v0 = *(const s16x8*)vrow;
      s16x8 v1 = *(const s16x8*)(vrow + 8);
#pragma unroll
      for (int j = 0; j < 8; ++j) Vt[(vdp * 16 + j) * 72 + vkv] = v0[j];
#pragma unroll
      for (int j = 0; j < 8; ++j) Vt[(vdp * 16 + 8 + j) * 72 + vkv] = v1[j];
    }
    __syncthreads();
#pragma unroll
    for (int sub = 0; sub < 4; ++sub) {
      const int kv0 = kb * 64 + sub * 16;
      const short* krow = qkv + (size_t)(sbase + kv0 + lr) * 3072 + 1024 + h * 64;
      const bf16x8 kf0 = *(const bf16x8*)(krow + lg * 8);
      const bf16x8 kf1 = *(const bf16x8*)(krow + 32 + lg * 8);
      f32x4 s = {};
      s = __builtin_amdgcn_mfma_f32_16x16x32_bf16(kf0, qf0, s, 0, 0, 0);
      s = __builtin_amdgcn_mfma_f32_16x16x32_bf16(kf1, qf1, s, 0, 0, 0);
      const float s0 = s[0] * 0.125f, s1 = s[1] * 0.125f;
      const float s2 = s[2] * 0.125f, s3 = s[3] * 0.125f;
      float tm = fmaxf(fmaxf(s0, s1), fmaxf(s2, s3));
      tm = fmaxf(tm, __shfl_xor(tm, 16));
      tm = fmaxf(tm, __shfl_xor(tm, 32));
      const float mn = fmaxf(mrun, tm);
      const float sc = __expf(mrun - mn);
      const float p0 = __expf(s0 - mn), p1 = __expf(s1 - mn);
      const float p2 = __expf(s2 - mn), p3 = __expf(s3 - mn);
      float ps = p0 + p1 + p2 + p3;
      ps += __shfl_xor(ps, 16);
      ps += __shfl_xor(ps, 32);
      lsum = lsum * sc + ps;
      mrun = mn;
      s16x4 pb;
      pb[0] = f2bs(p0); pb[1] = f2bs(p1); pb[2] = f2bs(p2); pb[3] = f2bs(p3);
#pragma unroll
      for (int f = 0; f < 4; ++f) {
        o[f][0] *= sc; o[f][1] *= sc; o[f][2] *= sc; o[f][3] *= sc;
        const s16x4 va = *(const s16x4*)&Vt[(f * 16 + lr) * 72 + sub * 16 + lg * 4];
        o[f] = __builtin_amdgcn_mfma_f32_16x16x16bf16_1k(va, pb, o[f], 0, 0, 0);
      }
    }
  }
  const float inv = 1.0f / lsum;
  short* orow = outp + (size_t)(sbase + q0 + lr) * 1024 + h * 64;
#pragma unroll
  for (int f = 0; f < 4; ++f) {
    s16x4 ov;
    ov[0] = f2bs(o[f][0] * inv); ov[1] = f2bs(o[f][1] * inv);
    ov[2] = f2bs(o[f][2] * inv); ov[3] = f2bs(o[f][3] * inv);
    *(s16x4*)(orow + f * 16 + lg * 4) = ov;
  }
}

// ---------------------------------------------------------------- launch
extern "C" void kernel_launch(void* const* d_in, const int* in_sizes, int n_in,
                              void* d_out, int out_size, void* d_ws, size_t ws_size,
                              hipStream_t stream) {
  const float* pixel  = (const float*)d_in[0];
  const float* conv_w = (const float*)d_in[2];
  const float* conv_b = (const float*)d_in[3];
  const float* pos_e  = (const float*)d_in[4];
  const float* ln1_g  = (const float*)d_in[5];
  const float* ln1_b  = (const float*)d_in[6];
  const float* qkv_w  = (const float*)d_in[7];
  const float* qkv_b  = (const float*)d_in[8];
  const float* proj_w = (const float*)d_in[9];
  const float* proj_b = (const float*)d_in[10];
  const float* ln2_g  = (const float*)d_in[11];
  const float* ln2_b  = (const float*)d_in[12];
  const float* fc1_w  = (const float*)d_in[13];
  const float* fc1_b  = (const float*)d_in[14];
  const float* fc2_w  = (const float*)d_in[15];
  const float* fc2_b  = (const float*)d_in[16];

  char* ws = (char*)d_ws;
  short* wQKV  = (short*)(ws + 0);           // 25165824
  short* wPROJ = (short*)(ws + 25165824);    // 8388608
  short* wFC1  = (short*)(ws + 33554432);    // 33554432
  short* wFC2  = (short*)(ws + 67108864);    // 33554432
  float* X     = (float*)(ws + 100663296);   // 16777216
  short* Y     = (short*)(ws + 117440512);   // 8388608
  short* QKVB  = (short*)(ws + 125829120);   // 25165824
  short* ATTNO = (short*)(ws + 150994944);   // 8388608  (end 159383552)
  short* H     = QKVB;                       // alias (33554432 = QKVB+ATTNO exactly)
  short* WPIX  = QKVB;                       // alias, used only before layer 0
  short* WCONV = (short*)(ws + 125829120 + 4980736);

  cvt_f32_bf16<<<2048, 256, 0, stream>>>(qkv_w, wQKV, 4 * 3072 * 1024);
  cvt_f32_bf16<<<1024, 256, 0, stream>>>(proj_w, wPROJ, 4 * 1024 * 1024);
  cvt_f32_bf16<<<2048, 256, 0, stream>>>(fc1_w, wFC1, 4 * 4096 * 1024);
  cvt_f32_bf16<<<2048, 256, 0, stream>>>(fc2_w, wFC2, 4 * 1024 * 4096);
  cvt_pad<<<4096, 256, 0, stream>>>(pixel, WPIX);
  cvt_pad<<<1024, 256, 0, stream>>>(conv_w, WCONV);

  gemm_bt<1024, 608, 3, 4, 8><<<256, 256, 0, stream>>>(WPIX, WCONV, conv_b, nullptr, X);
  pos_add<<<4096, 256, 0, stream>>>(X, pos_e);

  for (int i = 0; i < 4; ++i) {
    ln_fwd<<<4096, 256, 0, stream>>>(X, ln1_g + i * 1024, ln1_b + i * 1024, Y);
    gemm_bt<3072, 1024, 0, 8, 12><<<768, 256, 0, stream>>>(
        Y, wQKV + (size_t)i * 3072 * 1024, qkv_b + i * 3072, nullptr, QKVB);
    attn_fwd<<<dim3(16, 64), 256, 0, stream>>>(QKVB, ATTNO);
    gemm_bt<1024, 1024, 2, 4, 8><<<256, 256, 0, stream>>>(
        ATTNO, wPROJ + (size_t)i * 1024 * 1024, proj_b + i * 1024, X, X);
    ln_fwd<<<4096, 256, 0, stream>>>(X, ln2_g + i * 1024, ln2_b + i * 1024, Y);
    gemm_bt<4096, 1024, 1, 16, 8><<<1024, 256, 0, stream>>>(
        Y, wFC1 + (size_t)i * 4096 * 1024, fc1_b + i * 4096, nullptr, H);
    float* dest = (i < 3) ? X : (float*)d_out;
    gemm_bt<1024, 4096, 2, 4, 8><<<256, 256, 0, stream>>>(
        H, wFC2 + (size_t)i * 1024 * 4096, fc2_b + i * 1024, X, dest);
  }
}

// Round 4
// 1043.339 us; speedup vs baseline: 1.3016x; 1.1227x over previous
//
#include <hip/hip_runtime.h>
#include <math.h>

typedef __bf16 bf16x8 __attribute__((ext_vector_type(8)));
typedef float f32x4 __attribute__((ext_vector_type(4)));
typedef short s16x4 __attribute__((ext_vector_type(4)));
typedef short s16x8 __attribute__((ext_vector_type(8)));

static __device__ __forceinline__ short f2bs(float f) {
  return __builtin_bit_cast(short, (__bf16)f);
}

#define GLL16(gp, lp) __builtin_amdgcn_global_load_lds( \
    (const __attribute__((address_space(1))) void*)(gp), \
    (__attribute__((address_space(3))) void*)(lp), 16, 0, 0)

// ---------------------------------------------------------------- conversions
__global__ __launch_bounds__(256) void cvt_f32_bf16(const float* __restrict__ s,
                                                    short* __restrict__ d, int n) {
  int stride = gridDim.x * blockDim.x * 4;
  for (int j = (blockIdx.x * blockDim.x + threadIdx.x) * 4; j < n; j += stride) {
    float4 v = *(const float4*)(s + j);
    s16x4 o;
    o[0] = f2bs(v.x); o[1] = f2bs(v.y); o[2] = f2bs(v.z); o[3] = f2bs(v.w);
    *(s16x4*)(d + j) = o;
  }
}

// pad K 588 -> 608 with zeros, row-major
__global__ __launch_bounds__(256) void cvt_pad(const float* __restrict__ s,
                                               short* __restrict__ d) {
  int r = blockIdx.x;
  for (int c = threadIdx.x; c < 608; c += blockDim.x)
    d[(size_t)r * 608 + c] = (c < 588) ? f2bs(s[(size_t)r * 588 + c]) : (short)0;
}

// ---------------------------------------------------------------- GEMM
// C[M=4096,N] = A[M,K](bf16) @ B[N,K](bf16)^T + bias, epilogue variants.
// EPI: 0 = bf16 out, 1 = bf16 + exact GELU, 2 = f32 + residual, 3 = f32
// 3-deep prefetch pipeline, counted vmcnt (T3+T4).
template <int N, int K, int EPI, int CM, int CN>
__global__ __launch_bounds__(256) void gemm_bt(const short* __restrict__ A,
                                               const short* __restrict__ B,
                                               const float* __restrict__ bias,
                                               const float* __restrict__ resid,
                                               void* __restrict__ out) {
  static_assert(K % 32 == 0, "K");
  constexpr int NT = K / 32;
  static_assert(NT >= 3, "pipeline depth");
  constexpr int NX = N / 128, NY = 32;
  constexpr int nwg = NX * NY;
  static_assert(nwg % 8 == 0 && (nwg / 8) % (CM * CN) == 0, "chunk");
  static_assert(NX % CN == 0 && NY % CM == 0, "cells");
  __shared__ short lA[3][128 * 32];
  __shared__ short lB[3][128 * 32];

  const int o = blockIdx.x;
  const int wid = (o & 7) * (nwg / 8) + (o >> 3);
  constexpr int cellsz = CM * CN;
  const int cell = wid / cellsz, within = wid % cellsz;
  constexpr int cellsx = NX / CN;
  const int bm0 = ((cell / cellsx) * CM + within / CN) * 128;
  const int bn0 = ((cell % cellsx) * CN + within % CN) * 128;

  const int t = threadIdx.x, w = t >> 6, lane = t & 63;
  const int wr = w >> 1, wc = w & 1;
  f32x4 acc[4][4] = {};

  const int srow = t >> 2;
  const int scol = ((t & 3) ^ ((srow >> 1) & 3)) * 8;
  const short* aP = A + (size_t)(bm0 + srow) * K + scol;
  const short* bP = B + (size_t)(bn0 + srow) * K + scol;
  const int sdst0 = (w * 16) * 32;
  const int sdst1 = (64 + w * 16) * 32;

  const int lr = lane & 15;
  const int qx = ((lane >> 4) ^ ((lr >> 1) & 3)) * 8;

  auto stage = [&](int buf, int ko) {
    GLL16(aP + ko, &lA[buf][sdst0]);
    GLL16(aP + ko + (size_t)64 * K, &lA[buf][sdst1]);
    GLL16(bP + ko, &lB[buf][sdst0]);
    GLL16(bP + ko + (size_t)64 * K, &lB[buf][sdst1]);
  };

  stage(0, 0);
  stage(1, 32);
  stage(2, 64);

  int buf = 0;
  for (int kt = 0; kt < NT; ++kt) {
    if (kt < NT - 2)       asm volatile("s_waitcnt vmcnt(8)" ::: "memory");
    else if (kt == NT - 2) asm volatile("s_waitcnt vmcnt(4)" ::: "memory");
    else                   asm volatile("s_waitcnt vmcnt(0)" ::: "memory");
    __builtin_amdgcn_s_barrier();
    asm volatile("" ::: "memory");
    __builtin_amdgcn_sched_barrier(0);

    bf16x8 af[4], bg[4];
#pragma unroll
    for (int mi = 0; mi < 4; ++mi)
      af[mi] = *(const bf16x8*)&lA[buf][(wr * 64 + mi * 16 + lr) * 32 + qx];
#pragma unroll
    for (int ni = 0; ni < 4; ++ni)
      bg[ni] = *(const bf16x8*)&lB[buf][(wc * 64 + ni * 16 + lr) * 32 + qx];

    asm volatile("s_waitcnt lgkmcnt(0)" ::: "memory");
    __builtin_amdgcn_sched_barrier(0);
    __builtin_amdgcn_s_barrier();
    asm volatile("" ::: "memory");
    __builtin_amdgcn_sched_barrier(0);

    if (kt + 3 < NT) stage(buf, (kt + 3) * 32);
    __builtin_amdgcn_sched_barrier(0);

#pragma unroll
    for (int mi = 0; mi < 4; ++mi)
#pragma unroll
      for (int ni = 0; ni < 4; ++ni)
        acc[mi][ni] = __builtin_amdgcn_mfma_f32_16x16x32_bf16(af[mi], bg[ni],
                                                              acc[mi][ni], 0, 0, 0);
    buf = (buf == 2) ? 0 : buf + 1;
  }

  const int lg4 = (lane >> 4) * 4;
#pragma unroll
  for (int mi = 0; mi < 4; ++mi) {
#pragma unroll
    for (int ni = 0; ni < 4; ++ni) {
      const int row = bm0 + wr * 64 + mi * 16 + lg4;
      const int col = bn0 + wc * 64 + ni * 16 + lr;
      const float bc = bias[col];
#pragma unroll
      for (int r = 0; r < 4; ++r) {
        float v = acc[mi][ni][r] + bc;
        size_t idx = (size_t)(row + r) * N + col;
        if constexpr (EPI == 1) v = 0.5f * v * (1.0f + erff(v * 0.70710678118f));
        if constexpr (EPI == 0 || EPI == 1) ((short*)out)[idx] = f2bs(v);
        else if constexpr (EPI == 2) ((float*)out)[idx] = v + resid[idx];
        else ((float*)out)[idx] = v;
      }
    }
  }
}

// ---------------------------------------------------------------- LayerNorm -> bf16
__global__ __launch_bounds__(256) void ln_fwd(const float* __restrict__ x,
                                              const float* __restrict__ g,
                                              const float* __restrict__ b,
                                              short* __restrict__ y) {
  const int row = blockIdx.x, t = threadIdx.x, w = t >> 6, lane = t & 63;
  const float4 v = ((const float4*)(x + (size_t)row * 1024))[t];
  float s = v.x + v.y + v.z + v.w;
  float ss = v.x * v.x + v.y * v.y + v.z * v.z + v.w * v.w;
#pragma unroll
  for (int m = 1; m < 64; m <<= 1) { s += __shfl_xor(s, m); ss += __shfl_xor(ss, m); }
  __shared__ float rs[4], rss[4];
  if (lane == 0) { rs[w] = s; rss[w] = ss; }
  __syncthreads();
  s = rs[0] + rs[1] + rs[2] + rs[3];
  ss = rss[0] + rss[1] + rss[2] + rss[3];
  const float mean = s * (1.f / 1024.f);
  const float var = ss * (1.f / 1024.f) - mean * mean;
  const float rstd = rsqrtf(var + 1e-6f);
  const float4 gv = ((const float4*)g)[t];
  const float4 bv = ((const float4*)b)[t];
  s16x4 o;
  o[0] = f2bs((v.x - mean) * rstd * gv.x + bv.x);
  o[1] = f2bs((v.y - mean) * rstd * gv.y + bv.y);
  o[2] = f2bs((v.z - mean) * rstd * gv.z + bv.z);
  o[3] = f2bs((v.w - mean) * rstd * gv.w + bv.w);
  *(s16x4*)(y + (size_t)row * 1024 + t * 4) = o;
}

// ---------------------------------------------------------------- pos-embed bilinear add
__global__ __launch_bounds__(256) void pos_add(float* __restrict__ x,
                                               const float* __restrict__ pe) {
  const int sidx = blockIdx.x;
  const int f = sidx & 1023;
  const int wq = 2 * ((f >> 2) & 15) + (f & 1);
  const int hq = 2 * (f >> 6) + ((f >> 1) & 1);
  const float gx = (wq + 0.5f) * 0.75f - 0.5f;
  const float gy = (hq + 0.5f) * 0.75f - 0.5f;
  const float fx = floorf(gx), fy = floorf(gy);
  const float wx = gx - fx, wy = gy - fy;
  int x0 = (int)fx, y0 = (int)fy;
  const int x0i = x0 < 0 ? 0 : (x0 > 23 ? 23 : x0);
  const int x1i = (x0 + 1) < 0 ? 0 : ((x0 + 1) > 23 ? 23 : x0 + 1);
  const int y0i = y0 < 0 ? 0 : (y0 > 23 ? 23 : y0);
  const int y1i = (y0 + 1) < 0 ? 0 : ((y0 + 1) > 23 ? 23 : y0 + 1);
  const float w00 = (1 - wy) * (1 - wx), w01 = (1 - wy) * wx;
  const float w10 = wy * (1 - wx), w11 = wy * wx;
  const int c = threadIdx.x * 4;
  const float4 p00 = *(const float4*)(pe + (size_t)(y0i * 24 + x0i) * 1024 + c);
  const float4 p01 = *(const float4*)(pe + (size_t)(y0i * 24 + x1i) * 1024 + c);
  const float4 p10 = *(const float4*)(pe + (size_t)(y1i * 24 + x0i) * 1024 + c);
  const float4 p11 = *(const float4*)(pe + (size_t)(y1i * 24 + x1i) * 1024 + c);
  float* xp = x + (size_t)sidx * 1024 + c;
  float4 xv = *(float4*)xp;
  xv.x += w00 * p00.x + w01 * p01.x + w10 * p10.x + w11 * p11.x;
  xv.y += w00 * p00.y + w01 * p01.y + w10 * p10.y + w11 * p11.y;
  xv.z += w00 * p00.z + w01 * p01.z + w10 * p10.z + w11 * p11.z;
  xv.w += w00 * p00.w + w01 * p01.w + w10 * p10.w + w11 * p11.w;
  *(float4*)xp = xv;
}

// ---------------------------------------------------------------- attention (flash, swapped)
// qkv bf16 [4096][3072] (q|k|v each [NH=16][HD=64]); out bf16 [4096][1024]
// K: global_load_lds-staged [kv][d] tile, col-block ^= (row&7) (both sides).
// V: reg-staged transpose [d][kv] stride 72, kv ^= ((d>>4)<<4) -> per-d-block
//    bank windows (write-conflict fix). Double-buffered; 1 barrier per kb.
// Softmax: batched per 64-kv tile, exp2 domain, defer-max THR=12 (log2).
__global__ __launch_bounds__(256) void attn_fwd(const short* __restrict__ qkv,
                                                short* __restrict__ outp) {
  __shared__ short lK[2][64 * 64];
  __shared__ short Vt[2][64 * 72];
  const int t = threadIdx.x, w = t >> 6, lane = t & 63;
  const int b = blockIdx.y >> 4, h = blockIdx.y & 15;
  const int sbase = b * 1024;
  const int q0 = blockIdx.x * 64 + w * 16;
  const int lr = lane & 15, lg = lane >> 4;

  const short* qrow = qkv + (size_t)(sbase + q0 + lr) * 3072 + h * 64;
  const bf16x8 qf0 = *(const bf16x8*)(qrow + lg * 8);
  const bf16x8 qf1 = *(const bf16x8*)(qrow + 32 + lg * 8);

  // K staging: 2 passes of 32 rows; lane covers (row = base + t>>3, block = t&7)
  const int krofs = t >> 3;                         // 0..31
  const int kcol = ((t & 7) ^ (krofs & 7)) * 8;     // pre-swizzled source block
  const short* ksrc = qkv + (size_t)(sbase + krofs) * 3072 + 1024 + h * 64 + kcol;
  // V staging: lane holds kv = t>>2, d = (t&3)*16 .. +15
  const int vkv = t >> 2, vdp = t & 3;
  const short* vsrc = qkv + (size_t)(sbase + vkv) * 3072 + 2048 + h * 64 + vdp * 16;
  const int vph = vkv ^ (vdp << 4);                 // phys kv for Vt writes

  f32x4 o[4] = {};
  float mrun = -1e30f, lsum = 0.f;

  // ---- prologue: stage kb = 0
  s16x8 v0 = *(const s16x8*)vsrc;
  s16x8 v1 = *(const s16x8*)(vsrc + 8);
  GLL16(ksrc, &lK[0][(w * 8) * 64]);
  GLL16(ksrc + (size_t)32 * 3072, &lK[0][(32 + w * 8) * 64]);
#pragma unroll
  for (int j = 0; j < 8; ++j) Vt[0][(vdp * 16 + j) * 72 + vph] = v0[j];
#pragma unroll
  for (int j = 0; j < 8; ++j) Vt[0][(vdp * 16 + 8 + j) * 72 + vph] = v1[j];
  asm volatile("s_waitcnt vmcnt(0) lgkmcnt(0)" ::: "memory");
  __builtin_amdgcn_s_barrier();

  int buf = 0;
  for (int kb = 0; kb < 16; ++kb) {
    // issue next tile's global loads early (hide under compute)
    if (kb < 15) {
      const short* vs = vsrc + (size_t)(kb + 1) * 64 * 3072;
      v0 = *(const s16x8*)vs;
      v1 = *(const s16x8*)(vs + 8);
      const short* ks = ksrc + (size_t)(kb + 1) * 64 * 3072;
      GLL16(ks, &lK[buf ^ 1][(w * 8) * 64]);
      GLL16(ks + (size_t)32 * 3072, &lK[buf ^ 1][(32 + w * 8) * 64]);
    }

    // ---- QK^T: 4 sub-tiles of 16 kv
    f32x4 s[4];
    __builtin_amdgcn_s_setprio(1);
#pragma unroll
    for (int sub = 0; sub < 4; ++sub) {
      const int krow = (sub * 16 + lr) * 64;
      const bf16x8 kf0 = *(const bf16x8*)&lK[buf][krow + (lg ^ (lr & 7)) * 8];
      const bf16x8 kf1 = *(const bf16x8*)&lK[buf][krow + ((lg + 4) ^ (lr & 7)) * 8];
      f32x4 a = {};
      a = __builtin_amdgcn_mfma_f32_16x16x32_bf16(kf0, qf0, a, 0, 0, 0);
      a = __builtin_amdgcn_mfma_f32_16x16x32_bf16(kf1, qf1, a, 0, 0, 0);
      s[sub] = a;
    }
    __builtin_amdgcn_s_setprio(0);

    // ---- batched softmax (exp2 domain; scale*log2e folded)
    constexpr float SC = 0.125f * 1.44269504089f;
    float sl[16];
#pragma unroll
    for (int sub = 0; sub < 4; ++sub)
#pragma unroll
      for (int r = 0; r < 4; ++r) sl[sub * 4 + r] = s[sub][r] * SC;
    float tm = sl[0];
#pragma unroll
    for (int i = 1; i < 16; ++i) tm = fmaxf(tm, sl[i]);
    tm = fmaxf(tm, __shfl_xor(tm, 16));
    tm = fmaxf(tm, __shfl_xor(tm, 32));
    if (!__all(tm <= mrun + 12.0f)) {          // defer-max: rescale rarely
      const float newm = fmaxf(mrun, tm);
      const float sc = exp2f(mrun - newm);
      lsum *= sc;
#pragma unroll
      for (int f = 0; f < 4; ++f) {
        o[f][0] *= sc; o[f][1] *= sc; o[f][2] *= sc; o[f][3] *= sc;
      }
      mrun = newm;
    }
    s16x4 pb[4];
    float psum = 0.f;
#pragma unroll
    for (int sub = 0; sub < 4; ++sub)
#pragma unroll
      for (int r = 0; r < 4; ++r) {
        const float p = exp2f(sl[sub * 4 + r] - mrun);
        psum += p;
        pb[sub][r] = f2bs(p);
      }
    psum += __shfl_xor(psum, 16);
    psum += __shfl_xor(psum, 32);
    lsum += psum;

    // ---- PV
    __builtin_amdgcn_s_setprio(1);
#pragma unroll
    for (int f = 0; f < 4; ++f) {
      const int vrow = (f * 16 + lr) * 72;
#pragma unroll
      for (int sub = 0; sub < 4; ++sub) {
        const s16x4 va = *(const s16x4*)&Vt[buf][vrow + ((sub ^ f) << 4) + lg * 4];
        o[f] = __builtin_amdgcn_mfma_f32_16x16x16bf16_1k(va, pb[sub], o[f], 0, 0, 0);
      }
    }
    __builtin_amdgcn_s_setprio(0);

    // ---- finish staging kb+1 (compiler inserts the vmcnt wait for v0/v1)
    if (kb < 15) {
#pragma unroll
      for (int j = 0; j < 8; ++j) Vt[buf ^ 1][(vdp * 16 + j) * 72 + vph] = v0[j];
#pragma unroll
      for (int j = 0; j < 8; ++j) Vt[buf ^ 1][(vdp * 16 + 8 + j) * 72 + vph] = v1[j];
      asm volatile("s_waitcnt vmcnt(0) lgkmcnt(0)" ::: "memory");
      __builtin_amdgcn_s_barrier();
      buf ^= 1;
    }
  }

  const float inv = 1.0f / lsum;
  short* orow = outp + (size_t)(sbase + q0 + lr) * 1024 + h * 64;
#pragma unroll
  for (int f = 0; f < 4; ++f) {
    s16x4 ov;
    ov[0] = f2bs(o[f][0] * inv); ov[1] = f2bs(o[f][1] * inv);
    ov[2] = f2bs(o[f][2] * inv); ov[3] = f2bs(o[f][3] * inv);
    *(s16x4*)(orow + f * 16 + lg * 4) = ov;
  }
}

// ---------------------------------------------------------------- launch
extern "C" void kernel_launch(void* const* d_in, const int* in_sizes, int n_in,
                              void* d_out, int out_size, void* d_ws, size_t ws_size,
                              hipStream_t stream) {
  const float* pixel  = (const float*)d_in[0];
  const float* conv_w = (const float*)d_in[2];
  const float* conv_b = (const float*)d_in[3];
  const float* pos_e  = (const float*)d_in[4];
  const float* ln1_g  = (const float*)d_in[5];
  const float* ln1_b  = (const float*)d_in[6];
  const float* qkv_w  = (const float*)d_in[7];
  const float* qkv_b  = (const float*)d_in[8];
  const float* proj_w = (const float*)d_in[9];
  const float* proj_b = (const float*)d_in[10];
  const float* ln2_g  = (const float*)d_in[11];
  const float* ln2_b  = (const float*)d_in[12];
  const float* fc1_w  = (const float*)d_in[13];
  const float* fc1_b  = (const float*)d_in[14];
  const float* fc2_w  = (const float*)d_in[15];
  const float* fc2_b  = (const float*)d_in[16];

  char* ws = (char*)d_ws;
  short* wQKV  = (short*)(ws + 0);           // 25165824
  short* wPROJ = (short*)(ws + 25165824);    // 8388608
  short* wFC1  = (short*)(ws + 33554432);    // 33554432
  short* wFC2  = (short*)(ws + 67108864);    // 33554432
  float* X     = (float*)(ws + 100663296);   // 16777216
  short* Y     = (short*)(ws + 117440512);   // 8388608
  short* QKVB  = (short*)(ws + 125829120);   // 25165824
  short* ATTNO = (short*)(ws + 150994944);   // 8388608  (end 159383552)
  short* H     = QKVB;                       // alias
  short* WPIX  = QKVB;                       // alias, used only before layer 0
  short* WCONV = (short*)(ws + 125829120 + 4980736);

  cvt_f32_bf16<<<2048, 256, 0, stream>>>(qkv_w, wQKV, 4 * 3072 * 1024);
  cvt_f32_bf16<<<1024, 256, 0, stream>>>(proj_w, wPROJ, 4 * 1024 * 1024);
  cvt_f32_bf16<<<2048, 256, 0, stream>>>(fc1_w, wFC1, 4 * 4096 * 1024);
  cvt_f32_bf16<<<2048, 256, 0, stream>>>(fc2_w, wFC2, 4 * 1024 * 4096);
  cvt_pad<<<4096, 256, 0, stream>>>(pixel, WPIX);
  cvt_pad<<<1024, 256, 0, stream>>>(conv_w, WCONV);

  gemm_bt<1024, 608, 3, 4, 8><<<256, 256, 0, stream>>>(WPIX, WCONV, conv_b, nullptr, X);
  pos_add<<<4096, 256, 0, stream>>>(X, pos_e);

  for (int i = 0; i < 4; ++i) {
    ln_fwd<<<4096, 256, 0, stream>>>(X, ln1_g + i * 1024, ln1_b + i * 1024, Y);
    gemm_bt<3072, 1024, 0, 8, 12><<<768, 256, 0, stream>>>(
        Y, wQKV + (size_t)i * 3072 * 1024, qkv_b + i * 3072, nullptr, QKVB);
    attn_fwd<<<dim3(16, 64), 256, 0, stream>>>(QKVB, ATTNO);
    gemm_bt<1024, 1024, 2, 4, 8><<<256, 256, 0, stream>>>(
        ATTNO, wPROJ + (size_t)i * 1024 * 1024, proj_b + i * 1024, X, X);
    ln_fwd<<<4096, 256, 0, stream>>>(X, ln2_g + i * 1024, ln2_b + i * 1024, Y);
    gemm_bt<4096, 1024, 1, 16, 8><<<1024, 256, 0, stream>>>(
        Y, wFC1 + (size_t)i * 4096 * 1024, fc1_b + i * 4096, nullptr, H);
    float* dest = (i < 3) ? X : (float*)d_out;
    gemm_bt<1024, 4096, 2, 4, 8><<<256, 256, 0, stream>>>(
        H, wFC2 + (size_t)i * 1024 * 4096, fc2_b + i * 1024, X, dest);
  }
}